// Round 1
// baseline (871.311 us; speedup 1.0000x reference)
//
#include <hip/hip_runtime.h>

static constexpr int kNumUsers  = 100000;
static constexpr int kNumItems  = 50000;
static constexpr int kNTotal    = 150000;
static constexpr int kDim       = 64;
static constexpr int kStack     = 4;           // LAYERS+1
static constexpr int kEmbStride = kStack * kDim; // 256
static constexpr int kNnz       = 2000000;
static constexpr int kBatch     = 2048;
static constexpr int kNeg       = 16;
static constexpr unsigned kSeedHalf = 4194304u; // (2048*16*4*64)/2 = 2^22

// ---------------- Threefry-2x32 (JAX-compatible) ----------------

struct KeyPair { unsigned a, b; };

// constexpr version so the folded key bakes into the binary.
constexpr KeyPair tf2x32_const(unsigned k0, unsigned k1, unsigned x0, unsigned x1) {
  unsigned ks[3] = {k0, k1, k0 ^ k1 ^ 0x1BD11BDAu};
  const unsigned rots[2][4] = {{13u,15u,26u,6u},{17u,29u,16u,24u}};
  x0 += ks[0]; x1 += ks[1];
  for (int g = 0; g < 5; ++g) {
    for (int i = 0; i < 4; ++i) {
      unsigned r = rots[g & 1][i];
      x0 += x1;
      x1 = (x1 << r) | (x1 >> (32u - r));
      x1 ^= x0;
    }
    x0 += ks[(g + 1) % 3];
    x1 += ks[(g + 2) % 3] + (unsigned)(g + 1);
  }
  return {x0, x1};
}

// key = jax.random.fold_in(jax.random.key(42), 0)
//     = threefry2x32(key=(0,42), count=(0,0))
static constexpr KeyPair kFoldedKey = tf2x32_const(0u, 42u, 0u, 0u);

__device__ __forceinline__ unsigned rotl32(unsigned x, unsigned r) {
  return (x << r) | (x >> (32u - r));
}

__device__ __forceinline__ void tf2x32(unsigned k0, unsigned k1,
                                       unsigned x0, unsigned x1,
                                       unsigned& y0, unsigned& y1) {
  const unsigned ks2 = k0 ^ k1 ^ 0x1BD11BDAu;
  x0 += k0; x1 += k1;
#define TF_ROUND(r) { x0 += x1; x1 = rotl32(x1, (r)); x1 ^= x0; }
  TF_ROUND(13u) TF_ROUND(15u) TF_ROUND(26u) TF_ROUND(6u)
  x0 += k1;  x1 += ks2 + 1u;
  TF_ROUND(17u) TF_ROUND(29u) TF_ROUND(16u) TF_ROUND(24u)
  x0 += ks2; x1 += k0 + 2u;
  TF_ROUND(13u) TF_ROUND(15u) TF_ROUND(26u) TF_ROUND(6u)
  x0 += k0;  x1 += k1 + 3u;
  TF_ROUND(17u) TF_ROUND(29u) TF_ROUND(16u) TF_ROUND(24u)
  x0 += k1;  x1 += ks2 + 4u;
  TF_ROUND(13u) TF_ROUND(15u) TF_ROUND(26u) TF_ROUND(6u)
  x0 += ks2; x1 += k0 + 5u;
#undef TF_ROUND
  y0 = x0; y1 = x1;
}

// jax.random.uniform bit layout for a flat array of size 2^23:
// counts = iota, split into halves (x0 = [0,2^22), x1 = [2^22,2^23)),
// out = concat(y0_half, y1_half); float = bitcast((bits>>9)|0x3f800000)-1.
__device__ __forceinline__ float tf_uniform(unsigned i) {
  unsigned lo = (i < kSeedHalf) ? i : (i - kSeedHalf);
  unsigned hi = lo + kSeedHalf;
  unsigned y0, y1;
  tf2x32(kFoldedKey.a, kFoldedKey.b, lo, hi, y0, y1);
  unsigned bits = (i < kSeedHalf) ? y0 : y1;
  return __uint_as_float((bits >> 9) | 0x3F800000u) - 1.0f;
}

__device__ __forceinline__ float wred(float v) {
  for (int o = 32; o; o >>= 1) v += __shfl_xor(v, o, 64);
  return v;
}

// ---------------- kernels ----------------

__global__ void k_zero(int* __restrict__ deg, float* __restrict__ acc) {
  int i = blockIdx.x * blockDim.x + threadIdx.x;
  if (i < kNTotal) deg[i] = 0;
  if (i < 2) acc[i] = 0.0f;
}

__global__ void k_hist(const int* __restrict__ rows, int* __restrict__ deg) {
  int e = blockIdx.x * blockDim.x + threadIdx.x;
  if (e < kNnz) atomicAdd(&deg[rows[e]], 1);
}

__global__ void k_scan1(const int* __restrict__ deg, int* __restrict__ rptr,
                        int* __restrict__ bsum) {
  __shared__ int s[1024];
  int tid = threadIdx.x;
  int i = blockIdx.x * 1024 + tid;
  int v = (i < kNTotal) ? deg[i] : 0;
  s[tid] = v; __syncthreads();
  for (int off = 1; off < 1024; off <<= 1) {
    int t = (tid >= off) ? s[tid - off] : 0;
    __syncthreads();
    s[tid] += t;
    __syncthreads();
  }
  if (i < kNTotal) rptr[i] = s[tid] - v;       // exclusive within block
  if (tid == 1023) bsum[blockIdx.x] = s[1023]; // block total
}

__global__ void k_scan2(int* __restrict__ bsum, int nb) {
  __shared__ int s[256];
  int tid = threadIdx.x;
  int v = (tid < nb) ? bsum[tid] : 0;
  s[tid] = v; __syncthreads();
  for (int off = 1; off < 256; off <<= 1) {
    int t = (tid >= off) ? s[tid - off] : 0;
    __syncthreads();
    s[tid] += t;
    __syncthreads();
  }
  if (tid < nb) bsum[tid] = s[tid] - v;        // exclusive block offsets
}

__global__ void k_scan3(int* __restrict__ rptr, const int* __restrict__ bsum,
                        int* __restrict__ cursor) {
  int i = blockIdx.x * blockDim.x + threadIdx.x;
  if (i < kNTotal) {
    int val = rptr[i] + bsum[i >> 10];
    rptr[i] = val;
    cursor[i] = val;
  }
  if (i == 0) rptr[kNTotal] = kNnz;
}

__global__ void k_scatter(const int* __restrict__ rows, const int* __restrict__ cols,
                          const float* __restrict__ vals, int* __restrict__ cursor,
                          int* __restrict__ col2, float* __restrict__ val2) {
  int e = blockIdx.x * blockDim.x + threadIdx.x;
  if (e < kNnz) {
    int r = rows[e];
    int p = atomicAdd(&cursor[r], 1);
    col2[p] = cols[e];
    val2[p] = vals[e];
  }
}

__global__ void k_init_emb(const float* __restrict__ ue, const float* __restrict__ ie,
                           float* __restrict__ emb) {
  int i = blockIdx.x * blockDim.x + threadIdx.x;
  if (i < kNTotal * kDim) {
    int n = i >> 6, d = i & 63;
    float v = (n < kNumUsers) ? ue[n * kDim + d] : ie[(n - kNumUsers) * kDim + d];
    emb[n * kEmbStride + d] = v;  // layer 0, unscaled
  }
}

// One wave per row; lane = dim. Reads layer l slice, writes layer l+1 slice.
__global__ void k_spmm(const int* __restrict__ rptr, const int* __restrict__ col2,
                       const float* __restrict__ val2, float* __restrict__ emb, int l) {
  int row = blockIdx.x * 4 + (threadIdx.x >> 6);
  int lane = threadIdx.x & 63;
  if (row >= kNTotal) return;
  int s = rptr[row], t = rptr[row + 1];
  const float* src = emb + l * kDim;
  float acc = 0.0f;
  for (int e = s; e < t; ++e) {
    int c = col2[e];
    acc += val2[e] * src[c * kEmbStride + lane];
  }
  emb[row * kEmbStride + (l + 1) * kDim + lane] = acc;
}

__global__ void __launch_bounds__(256)
k_batch(const float* __restrict__ emb, const int* __restrict__ uidx,
        const int* __restrict__ pidx, const int* __restrict__ nidx,
        float* __restrict__ acc) {
  const float LAM[4] = {0.25f, 0.5f, 0.75f, 1.0f};
  int b = blockIdx.x;
  int lane = threadIdx.x & 63;
  int w = threadIdx.x >> 6;

  __shared__ float s_score[kNeg][kStack];
  __shared__ float s_sq0[kNeg];
  __shared__ float s_pos, s_usq, s_psq;

  int un = uidx[b];
  int pn = kNumUsers + pidx[b];
  float u[4], p[4];
#pragma unroll
  for (int l = 0; l < 4; ++l) {
    u[l] = emb[un * kEmbStride + l * kDim + lane] * LAM[l];
    p[l] = emb[pn * kEmbStride + l * kDim + lane] * LAM[l];
  }

  if (w == 0) {
    float ps = wred(u[0]*p[0] + u[1]*p[1] + u[2]*p[2] + u[3]*p[3]);
    float uq = wred(u[0] * u[0]);
    float pq = wred(p[0] * p[0]);
    if (lane == 0) { s_pos = ps; s_usq = uq; s_psq = pq; }
  }

#pragma unroll
  for (int j = 0; j < 4; ++j) {
    int c = w * 4 + j;
    int nn = kNumUsers + nidx[b * kNeg + c];
#pragma unroll
    for (int l = 0; l < 4; ++l) {
      float nv = emb[nn * kEmbStride + l * kDim + lane] * LAM[l];
      unsigned si = ((unsigned)(b * kNeg + c) * 4u + (unsigned)l) * 64u + (unsigned)lane;
      float sd = tf_uniform(si);
      float nm = sd * p[l] + (1.0f - sd) * nv;   // interpolated negative
      float sc = wred(u[l] * nm);
      if (l == 0) {
        float q = wred(nm * nm);
        if (lane == 0) s_sq0[c] = q;
      }
      if (lane == 0) s_score[c][l] = sc;
    }
  }
  __syncthreads();

  if (threadIdx.x == 0) {
    float negsc = 0.0f; int idx0 = 0;
#pragma unroll
    for (int l = 0; l < 4; ++l) {
      float m = s_score[0][l]; int mi = 0;
      for (int c = 1; c < kNeg; ++c) {
        float v = s_score[c][l];
        if (v > m) { m = v; mi = c; }   // first-max tie-break, like jnp.argmax
      }
      negsc += m;
      if (l == 0) idx0 = mi;
    }
    float x = negsc - s_pos;
    float term = logf(1.0f + expf(x));
    float reg = 0.5f * (s_usq + s_psq + s_sq0[idx0]);
    atomicAdd(&acc[0], term);
    atomicAdd(&acc[1], reg);
  }
}

__global__ void k_final(const float* __restrict__ acc, float* __restrict__ out) {
  if (threadIdx.x == 0 && blockIdx.x == 0) {
    out[0] = acc[0] / (float)kBatch;
    out[1] = acc[1] / (float)kBatch;
  }
}

// ---------------- launch ----------------

extern "C" void kernel_launch(void* const* d_in, const int* in_sizes, int n_in,
                              void* d_out, int out_size, void* d_ws, size_t ws_size,
                              hipStream_t stream) {
  const float* ue   = (const float*)d_in[0];
  const float* ie   = (const float*)d_in[1];
  const float* gv   = (const float*)d_in[2];
  const int*   gr   = (const int*)d_in[3];
  const int*   gc   = (const int*)d_in[4];
  const int*   uidx = (const int*)d_in[5];
  const int*   pidx = (const int*)d_in[6];
  const int*   nidx = (const int*)d_in[7];
  float* out = (float*)d_out;

  char* ws = (char*)d_ws;
  size_t off = 0;
  auto alloc = [&](size_t bytes) -> void* {
    off = (off + 255) & ~(size_t)255;
    void* p = ws + off;
    off += bytes;
    return p;
  };
  float* emb   = (float*)alloc((size_t)kNTotal * kEmbStride * sizeof(float)); // 153.6 MB
  int*   rptr  = (int*)  alloc((size_t)(kNTotal + 1) * sizeof(int));
  int*   cursor= (int*)  alloc((size_t)kNTotal * sizeof(int));
  int*   deg   = (int*)  alloc((size_t)kNTotal * sizeof(int));
  int*   col2  = (int*)  alloc((size_t)kNnz * sizeof(int));
  float* val2  = (float*)alloc((size_t)kNnz * sizeof(float));
  int*   bsum  = (int*)  alloc(1024 * sizeof(int));
  float* acc   = (float*)alloc(16 * sizeof(float));
  (void)ws_size; (void)in_sizes; (void)n_in; (void)out_size;

  const int nb1 = (kNTotal + 1023) / 1024; // 147

  hipLaunchKernelGGL(k_zero,    dim3((kNTotal + 255) / 256), dim3(256), 0, stream, deg, acc);
  hipLaunchKernelGGL(k_hist,    dim3((kNnz + 255) / 256),    dim3(256), 0, stream, gr, deg);
  hipLaunchKernelGGL(k_scan1,   dim3(nb1),                   dim3(1024), 0, stream, deg, rptr, bsum);
  hipLaunchKernelGGL(k_scan2,   dim3(1),                     dim3(256), 0, stream, bsum, nb1);
  hipLaunchKernelGGL(k_scan3,   dim3((kNTotal + 255) / 256), dim3(256), 0, stream, rptr, bsum, cursor);
  hipLaunchKernelGGL(k_scatter, dim3((kNnz + 255) / 256),    dim3(256), 0, stream, gr, gc, gv, cursor, col2, val2);
  hipLaunchKernelGGL(k_init_emb,dim3((kNTotal * kDim + 255) / 256), dim3(256), 0, stream, ue, ie, emb);
  for (int l = 0; l < 3; ++l)
    hipLaunchKernelGGL(k_spmm,  dim3((kNTotal + 3) / 4),     dim3(256), 0, stream, rptr, col2, val2, emb, l);
  hipLaunchKernelGGL(k_batch,   dim3(kBatch),                dim3(256), 0, stream, emb, uidx, pidx, nidx, acc);
  hipLaunchKernelGGL(k_final,   dim3(1),                     dim3(1),   0, stream, acc, out);
}

// Round 2
// 556.735 us; speedup vs baseline: 1.5650x; 1.5650x over previous
//
#include <hip/hip_runtime.h>

static constexpr int kNumUsers  = 100000;
static constexpr int kNumItems  = 50000;
static constexpr int kNTotal    = 150000;
static constexpr int kDim       = 64;
static constexpr int kNnz       = 2000000;
static constexpr int kBatch     = 2048;
static constexpr int kNeg       = 16;
static constexpr int kLayerStride = kNTotal * kDim; // floats per layer slice
static constexpr unsigned kSeedHalf = 4194304u;     // (2048*16*4*64)/2 = 2^22

// ---------------- Threefry-2x32 (JAX-compatible) ----------------

struct KeyPair { unsigned a, b; };

constexpr KeyPair tf2x32_const(unsigned k0, unsigned k1, unsigned x0, unsigned x1) {
  unsigned ks[3] = {k0, k1, k0 ^ k1 ^ 0x1BD11BDAu};
  const unsigned rots[2][4] = {{13u,15u,26u,6u},{17u,29u,16u,24u}};
  x0 += ks[0]; x1 += ks[1];
  for (int g = 0; g < 5; ++g) {
    for (int i = 0; i < 4; ++i) {
      unsigned r = rots[g & 1][i];
      x0 += x1;
      x1 = (x1 << r) | (x1 >> (32u - r));
      x1 ^= x0;
    }
    x0 += ks[(g + 1) % 3];
    x1 += ks[(g + 2) % 3] + (unsigned)(g + 1);
  }
  return {x0, x1};
}

// key = jax.random.fold_in(jax.random.key(42), 0) = threefry2x32(key=(0,42), count=(0,0))
static constexpr KeyPair kFoldedKey = tf2x32_const(0u, 42u, 0u, 0u);

__device__ __forceinline__ unsigned rotl32(unsigned x, unsigned r) {
  return (x << r) | (x >> (32u - r));
}

__device__ __forceinline__ void tf2x32(unsigned k0, unsigned k1,
                                       unsigned x0, unsigned x1,
                                       unsigned& y0, unsigned& y1) {
  const unsigned ks2 = k0 ^ k1 ^ 0x1BD11BDAu;
  x0 += k0; x1 += k1;
#define TF_ROUND(r) { x0 += x1; x1 = rotl32(x1, (r)); x1 ^= x0; }
  TF_ROUND(13u) TF_ROUND(15u) TF_ROUND(26u) TF_ROUND(6u)
  x0 += k1;  x1 += ks2 + 1u;
  TF_ROUND(17u) TF_ROUND(29u) TF_ROUND(16u) TF_ROUND(24u)
  x0 += ks2; x1 += k0 + 2u;
  TF_ROUND(13u) TF_ROUND(15u) TF_ROUND(26u) TF_ROUND(6u)
  x0 += k0;  x1 += k1 + 3u;
  TF_ROUND(17u) TF_ROUND(29u) TF_ROUND(16u) TF_ROUND(24u)
  x0 += k1;  x1 += ks2 + 4u;
  TF_ROUND(13u) TF_ROUND(15u) TF_ROUND(26u) TF_ROUND(6u)
  x0 += ks2; x1 += k0 + 5u;
#undef TF_ROUND
  y0 = x0; y1 = x1;
}

__device__ __forceinline__ float tf_uniform(unsigned i) {
  unsigned lo = (i < kSeedHalf) ? i : (i - kSeedHalf);
  unsigned hi = lo + kSeedHalf;
  unsigned y0, y1;
  tf2x32(kFoldedKey.a, kFoldedKey.b, lo, hi, y0, y1);
  unsigned bits = (i < kSeedHalf) ? y0 : y1;
  return __uint_as_float((bits >> 9) | 0x3F800000u) - 1.0f;
}

__device__ __forceinline__ float wred(float v) {
  for (int o = 32; o; o >>= 1) v += __shfl_xor(v, o, 64);
  return v;
}

// ---------------- kernels ----------------

__global__ void k_zero(int* __restrict__ deg, float* __restrict__ acc) {
  int i = blockIdx.x * blockDim.x + threadIdx.x;
  if (i < kNTotal) deg[i] = 0;
  if (i < 2) acc[i] = 0.0f;
}

__global__ void k_hist(const int* __restrict__ rows, int* __restrict__ deg) {
  int e = blockIdx.x * blockDim.x + threadIdx.x;
  if (e < kNnz) atomicAdd(&deg[rows[e]], 1);
}

__global__ void k_scan1(const int* __restrict__ deg, int* __restrict__ rptr,
                        int* __restrict__ bsum) {
  __shared__ int s[1024];
  int tid = threadIdx.x;
  int i = blockIdx.x * 1024 + tid;
  int v = (i < kNTotal) ? deg[i] : 0;
  s[tid] = v; __syncthreads();
  for (int off = 1; off < 1024; off <<= 1) {
    int t = (tid >= off) ? s[tid - off] : 0;
    __syncthreads();
    s[tid] += t;
    __syncthreads();
  }
  if (i < kNTotal) rptr[i] = s[tid] - v;
  if (tid == 1023) bsum[blockIdx.x] = s[1023];
}

__global__ void k_scan2(int* __restrict__ bsum, int nb) {
  __shared__ int s[256];
  int tid = threadIdx.x;
  int v = (tid < nb) ? bsum[tid] : 0;
  s[tid] = v; __syncthreads();
  for (int off = 1; off < 256; off <<= 1) {
    int t = (tid >= off) ? s[tid - off] : 0;
    __syncthreads();
    s[tid] += t;
    __syncthreads();
  }
  if (tid < nb) bsum[tid] = s[tid] - v;
}

__global__ void k_scan3(int* __restrict__ rptr, const int* __restrict__ bsum,
                        int* __restrict__ cursor) {
  int i = blockIdx.x * blockDim.x + threadIdx.x;
  if (i < kNTotal) {
    int val = rptr[i] + bsum[i >> 10];
    rptr[i] = val;
    cursor[i] = val;
  }
  if (i == 0) rptr[kNTotal] = kNnz;
}

__global__ void k_scatter(const int* __restrict__ rows, const int* __restrict__ cols,
                          const float* __restrict__ vals, int* __restrict__ cursor,
                          int* __restrict__ col2, float* __restrict__ val2) {
  int e = blockIdx.x * blockDim.x + threadIdx.x;
  if (e < kNnz) {
    int r = rows[e];
    int p = atomicAdd(&cursor[r], 1);
    col2[p] = cols[e];
    val2[p] = vals[e];
  }
}

__global__ void k_init_emb(const float* __restrict__ ue, const float* __restrict__ ie,
                           float* __restrict__ emb0) {
  int i = blockIdx.x * blockDim.x + threadIdx.x;
  if (i < kNTotal * kDim) {
    int n = i >> 6, d = i & 63;
    emb0[i] = (n < kNumUsers) ? ue[n * kDim + d] : ie[(n - kNumUsers) * kDim + d];
  }
}

// 4 rows per wave: 16 lanes x float4 per row. 2-way edge unroll for MLP.
__global__ void __launch_bounds__(256)
k_spmm(const int* __restrict__ rptr, const int* __restrict__ col2,
       const float* __restrict__ val2, const float* __restrict__ src,
       float* __restrict__ dst) {
  int row  = blockIdx.x * 16 + (threadIdx.x >> 4);
  int lane = threadIdx.x & 15;
  if (row >= kNTotal) return;
  int s = rptr[row], t = rptr[row + 1];
  const float4* __restrict__ src4 = (const float4*)src;
  float4 acc = make_float4(0.f, 0.f, 0.f, 0.f);
  int e = s;
  for (; e + 1 < t; e += 2) {
    int   c0 = col2[e],     c1 = col2[e + 1];
    float v0 = val2[e],     v1 = val2[e + 1];
    float4 a = src4[(size_t)c0 * 16 + lane];
    float4 b = src4[(size_t)c1 * 16 + lane];
    acc.x += v0 * a.x; acc.y += v0 * a.y; acc.z += v0 * a.z; acc.w += v0 * a.w;
    acc.x += v1 * b.x; acc.y += v1 * b.y; acc.z += v1 * b.z; acc.w += v1 * b.w;
  }
  if (e < t) {
    int   c0 = col2[e];
    float v0 = val2[e];
    float4 a = src4[(size_t)c0 * 16 + lane];
    acc.x += v0 * a.x; acc.y += v0 * a.y; acc.z += v0 * a.z; acc.w += v0 * a.w;
  }
  ((float4*)dst)[(size_t)row * 16 + lane] = acc;
}

__global__ void __launch_bounds__(256)
k_batch(const float* __restrict__ emb, const int* __restrict__ uidx,
        const int* __restrict__ pidx, const int* __restrict__ nidx,
        float* __restrict__ acc) {
  const float LAM[4] = {0.25f, 0.5f, 0.75f, 1.0f};
  int b = blockIdx.x;
  int lane = threadIdx.x & 63;
  int w = threadIdx.x >> 6;

  __shared__ float s_score[kNeg][4];
  __shared__ float s_sq0[kNeg];
  __shared__ float s_pos, s_usq, s_psq;

  int un = uidx[b];
  int pn = kNumUsers + pidx[b];
  float u[4], p[4];
#pragma unroll
  for (int l = 0; l < 4; ++l) {
    u[l] = emb[(size_t)l * kLayerStride + (size_t)un * kDim + lane] * LAM[l];
    p[l] = emb[(size_t)l * kLayerStride + (size_t)pn * kDim + lane] * LAM[l];
  }

  if (w == 0) {
    float ps = wred(u[0]*p[0] + u[1]*p[1] + u[2]*p[2] + u[3]*p[3]);
    float uq = wred(u[0] * u[0]);
    float pq = wred(p[0] * p[0]);
    if (lane == 0) { s_pos = ps; s_usq = uq; s_psq = pq; }
  }

#pragma unroll
  for (int j = 0; j < 4; ++j) {
    int c = w * 4 + j;
    int nn = kNumUsers + nidx[b * kNeg + c];
#pragma unroll
    for (int l = 0; l < 4; ++l) {
      float nv = emb[(size_t)l * kLayerStride + (size_t)nn * kDim + lane] * LAM[l];
      unsigned si = ((unsigned)(b * kNeg + c) * 4u + (unsigned)l) * 64u + (unsigned)lane;
      float sd = tf_uniform(si);
      float nm = sd * p[l] + (1.0f - sd) * nv;
      float sc = wred(u[l] * nm);
      if (l == 0) {
        float q = wred(nm * nm);
        if (lane == 0) s_sq0[c] = q;
      }
      if (lane == 0) s_score[c][l] = sc;
    }
  }
  __syncthreads();

  if (threadIdx.x == 0) {
    float negsc = 0.0f; int idx0 = 0;
#pragma unroll
    for (int l = 0; l < 4; ++l) {
      float m = s_score[0][l]; int mi = 0;
      for (int c = 1; c < kNeg; ++c) {
        float v = s_score[c][l];
        if (v > m) { m = v; mi = c; }
      }
      negsc += m;
      if (l == 0) idx0 = mi;
    }
    float x = negsc - s_pos;
    float term = logf(1.0f + expf(x));
    float reg = 0.5f * (s_usq + s_psq + s_sq0[idx0]);
    atomicAdd(&acc[0], term);
    atomicAdd(&acc[1], reg);
  }
}

__global__ void k_final(const float* __restrict__ acc, float* __restrict__ out) {
  if (threadIdx.x == 0 && blockIdx.x == 0) {
    out[0] = acc[0] / (float)kBatch;
    out[1] = acc[1] / (float)kBatch;
  }
}

// ---------------- launch ----------------

extern "C" void kernel_launch(void* const* d_in, const int* in_sizes, int n_in,
                              void* d_out, int out_size, void* d_ws, size_t ws_size,
                              hipStream_t stream) {
  const float* ue   = (const float*)d_in[0];
  const float* ie   = (const float*)d_in[1];
  const float* gv   = (const float*)d_in[2];
  const int*   gr   = (const int*)d_in[3];
  const int*   gc   = (const int*)d_in[4];
  const int*   uidx = (const int*)d_in[5];
  const int*   pidx = (const int*)d_in[6];
  const int*   nidx = (const int*)d_in[7];
  float* out = (float*)d_out;

  char* ws = (char*)d_ws;
  size_t off = 0;
  auto alloc = [&](size_t bytes) -> void* {
    off = (off + 255) & ~(size_t)255;
    void* p = ws + off;
    off += bytes;
    return p;
  };
  // 4 contiguous per-layer slices: emb + l*kLayerStride
  float* emb   = (float*)alloc((size_t)4 * kLayerStride * sizeof(float)); // 153.6 MB
  int*   rptr  = (int*)  alloc((size_t)(kNTotal + 1) * sizeof(int));
  int*   cursor= (int*)  alloc((size_t)kNTotal * sizeof(int));
  int*   deg   = (int*)  alloc((size_t)kNTotal * sizeof(int));
  int*   col2  = (int*)  alloc((size_t)kNnz * sizeof(int));
  float* val2  = (float*)alloc((size_t)kNnz * sizeof(float));
  int*   bsum  = (int*)  alloc(1024 * sizeof(int));
  float* acc   = (float*)alloc(16 * sizeof(float));
  (void)ws_size; (void)in_sizes; (void)n_in; (void)out_size;

  const int nb1 = (kNTotal + 1023) / 1024; // 147

  hipLaunchKernelGGL(k_zero,    dim3((kNTotal + 255) / 256), dim3(256), 0, stream, deg, acc);
  hipLaunchKernelGGL(k_hist,    dim3((kNnz + 255) / 256),    dim3(256), 0, stream, gr, deg);
  hipLaunchKernelGGL(k_scan1,   dim3(nb1),                   dim3(1024), 0, stream, deg, rptr, bsum);
  hipLaunchKernelGGL(k_scan2,   dim3(1),                     dim3(256), 0, stream, bsum, nb1);
  hipLaunchKernelGGL(k_scan3,   dim3((kNTotal + 255) / 256), dim3(256), 0, stream, rptr, bsum, cursor);
  hipLaunchKernelGGL(k_scatter, dim3((kNnz + 255) / 256),    dim3(256), 0, stream, gr, gc, gv, cursor, col2, val2);
  hipLaunchKernelGGL(k_init_emb,dim3((kNTotal * kDim + 255) / 256), dim3(256), 0, stream, ue, ie, emb);
  for (int l = 0; l < 3; ++l)
    hipLaunchKernelGGL(k_spmm,  dim3((kNTotal + 15) / 16),   dim3(256), 0, stream,
                       rptr, col2, val2,
                       emb + (size_t)l * kLayerStride,
                       emb + (size_t)(l + 1) * kLayerStride);
  hipLaunchKernelGGL(k_batch,   dim3(kBatch),                dim3(256), 0, stream, emb, uidx, pidx, nidx, acc);
  hipLaunchKernelGGL(k_final,   dim3(1),                     dim3(1),   0, stream, acc, out);
}